// Round 10
// baseline (429.291 us; speedup 1.0000x reference)
//
#include <hip/hip_runtime.h>
#include <math.h>

// Problem constants (from reference): B=2, S=2048, D=1024, H=16, DH=64
#define BATCH 2
#define SEQ 2048
#define DMODEL 1024
#define NHEAD 16
#define DHEAD 64
#define QKV_COLS (3 * DMODEL)          // 3072
#define EPS 1e-8f
#define LOG2E 1.44269504f

typedef short bf16x8 __attribute__((ext_vector_type(8)));   // 8 bf16 (4 VGPRs)
typedef float f32x4 __attribute__((ext_vector_type(4)));    // 4 fp32 acc

// round-to-nearest-even float -> bf16 (as raw ushort)
static __device__ __forceinline__ unsigned short f2bf(float x) {
  unsigned u = __float_as_uint(x);
  u += 0x7fffu + ((u >> 16) & 1u);
  return (unsigned short)(u >> 16);
}

// pack two f32 -> (bf16(hi)<<16)|bf16(lo) in 3 VALU (round-half-up + v_perm)
static __device__ __forceinline__ unsigned pkbf(float lo, float hi) {
  const unsigned ul = __float_as_uint(lo) + 0x8000u;
  const unsigned uh = __float_as_uint(hi) + 0x8000u;
  return __builtin_amdgcn_perm(uh, ul, 0x07060302);  // [uh.hi16 | ul.hi16]
}

// async global->LDS, 16 B per lane (global_load_lds_dwordx4).
// LDS dest: wave-uniform base + lane*16 (m104/m108).
static __device__ __forceinline__ void async_ld16(const unsigned short* g,
                                                  unsigned short* l) {
  __builtin_amdgcn_global_load_lds(
      (const __attribute__((address_space(1))) void*)g,
      (__attribute__((address_space(3))) void*)(unsigned int)(unsigned long long)l,
      16, 0, 0);
}

// ---------------------------------------------------------------------------
// Prep 1: x f32 [M][K] -> bf16 same layout. 4 floats/thread.
// ---------------------------------------------------------------------------
__global__ __launch_bounds__(256) void convert_x_kernel(
    const float* __restrict__ x, unsigned short* __restrict__ xb) {
  const size_t i = ((size_t)blockIdx.x * 256 + threadIdx.x) * 4;
  const float4 a = *(const float4*)(x + i);
  ushort4 r;
  r.x = f2bf(a.x); r.y = f2bf(a.y); r.z = f2bf(a.z); r.w = f2bf(a.w);
  *(ushort4*)(xb + i) = r;
}

// ---------------------------------------------------------------------------
// Prep 2 (fused): both weight transposes in one launch.
// ---------------------------------------------------------------------------
__global__ __launch_bounds__(256) void transpose_w2_kernel(
    const float* __restrict__ W0, unsigned short* __restrict__ Wt0,
    const float* __restrict__ W1, unsigned short* __restrict__ Wt1) {
  __shared__ float tile[32][33];
  const int bx = blockIdx.x;
  const float* W;
  unsigned short* Wt;
  int N, n0;
  if (bx < 96) { W = W0; Wt = Wt0; N = QKV_COLS; n0 = bx * 32; }
  else         { W = W1; Wt = Wt1; N = DMODEL;   n0 = (bx - 96) * 32; }
  const int K = DMODEL;
  const int k0 = blockIdx.y * 32;
  const int tx = threadIdx.x, ty = threadIdx.y;
#pragma unroll
  for (int i = 0; i < 4; ++i)
    tile[ty + i * 8][tx] = W[(size_t)(k0 + ty + i * 8) * N + n0 + tx];
  __syncthreads();
#pragma unroll
  for (int i = 0; i < 4; ++i)
    Wt[(size_t)(n0 + ty + i * 8) * K + k0 + tx] = f2bf(tile[tx][ty + i * 8]);
}

// ---------------------------------------------------------------------------
// bf16 MFMA GEMM, double-buffered staging. C = A @ Bt^T. Used for GEMM2.
// ---------------------------------------------------------------------------
__global__ __launch_bounds__(256) void sgemm_bf16_kernel(
    const unsigned short* __restrict__ A, const unsigned short* __restrict__ Bt,
    float* __restrict__ C, int M, int N, int K) {
  __shared__ unsigned short As[2][128 * 32];   // [buf][m][k]
  __shared__ unsigned short Bs[2][128 * 32];   // [buf][n][k]

  const int t = threadIdx.x;
  const int w = t >> 6;
  const int lane = t & 63;
  const int quad = lane >> 4;
  const int lr = lane & 15;
  const int wr = w >> 1, wc = w & 1;
  const int m0 = blockIdx.y * 128;
  const int n0 = blockIdx.x * 128;

  const int srow = w * 32 + (lane >> 2);
  const int scol = (lane & 3) * 8;
  const unsigned short* ga = A + (size_t)(m0 + srow) * K + scol;
  const unsigned short* gb = Bt + (size_t)(n0 + srow) * K + scol;

  auto stage = [&](int k0, int bb) {
#pragma unroll
    for (int i = 0; i < 2; ++i) {
      async_ld16(ga + (size_t)(i * 16) * K + k0, &As[bb][(w * 32 + i * 16) * 32]);
      async_ld16(gb + (size_t)(i * 16) * K + k0, &Bs[bb][(w * 32 + i * 16) * 32]);
    }
  };

  f32x4 acc[4][4];
  const f32x4 zero4 = {0.f, 0.f, 0.f, 0.f};
#pragma unroll
  for (int i = 0; i < 4; ++i)
#pragma unroll
    for (int j = 0; j < 4; ++j) acc[i][j] = zero4;

  stage(0, 0);
  int bb = 0;
  for (int k0 = 0; k0 < K; k0 += 32, bb ^= 1) {
    __syncthreads();
    if (k0 + 32 < K) stage(k0 + 32, bb ^ 1);

    bf16x8 af[4], bfr[4];
#pragma unroll
    for (int i = 0; i < 4; ++i)
      af[i] = *(const bf16x8*)&As[bb][(wr * 64 + i * 16 + lr) * 32 + quad * 8];
#pragma unroll
    for (int j = 0; j < 4; ++j)
      bfr[j] = *(const bf16x8*)&Bs[bb][(wc * 64 + j * 16 + lr) * 32 + quad * 8];
#pragma unroll
    for (int i = 0; i < 4; ++i)
#pragma unroll
      for (int j = 0; j < 4; ++j)
        acc[i][j] = __builtin_amdgcn_mfma_f32_16x16x32_bf16(af[i], bfr[j], acc[i][j], 0, 0, 0);
  }

#pragma unroll
  for (int i = 0; i < 4; ++i)
#pragma unroll
    for (int r = 0; r < 4; ++r) {
      float* c = C + (size_t)(m0 + wr * 64 + i * 16 + quad * 4 + r) * N + n0 + wc * 64 + lr;
#pragma unroll
      for (int j = 0; j < 4; ++j) c[j * 16] = acc[i][j][r];
    }
}

// ---------------------------------------------------------------------------
// GEMM1 + fused qk-norm, double-buffered. Writes bf16 Qh/Kh/Vh [B,H,S,DH].
// ---------------------------------------------------------------------------
__global__ __launch_bounds__(256) void qkv_gemm_norm_kernel(
    const unsigned short* __restrict__ A, const unsigned short* __restrict__ Bt,
    const float* __restrict__ tau,
    unsigned short* __restrict__ Qh, unsigned short* __restrict__ Kh,
    unsigned short* __restrict__ Vh) {
  __shared__ unsigned short As[2][128 * 32];
  __shared__ unsigned short Bs[2][128 * 32];

  const int K = DMODEL, N = QKV_COLS;
  const int t = threadIdx.x;
  const int w = t >> 6;
  const int lane = t & 63;
  const int quad = lane >> 4;
  const int lr = lane & 15;
  const int wr = w >> 1, wc = w & 1;
  const int m0 = blockIdx.y * 128;
  const int n0 = blockIdx.x * 128;

  const int srow = w * 32 + (lane >> 2);
  const int scol = (lane & 3) * 8;
  const unsigned short* ga = A + (size_t)(m0 + srow) * K + scol;
  const unsigned short* gb = Bt + (size_t)(n0 + srow) * K + scol;

  auto stage = [&](int k0, int bb) {
#pragma unroll
    for (int i = 0; i < 2; ++i) {
      async_ld16(ga + (size_t)(i * 16) * K + k0, &As[bb][(w * 32 + i * 16) * 32]);
      async_ld16(gb + (size_t)(i * 16) * K + k0, &Bs[bb][(w * 32 + i * 16) * 32]);
    }
  };

  f32x4 acc[4][4];
  const f32x4 zero4 = {0.f, 0.f, 0.f, 0.f};
#pragma unroll
  for (int i = 0; i < 4; ++i)
#pragma unroll
    for (int j = 0; j < 4; ++j) acc[i][j] = zero4;

  stage(0, 0);
  int bb = 0;
  for (int k0 = 0; k0 < K; k0 += 32, bb ^= 1) {
    __syncthreads();
    if (k0 + 32 < K) stage(k0 + 32, bb ^ 1);

    bf16x8 af[4], bfr[4];
#pragma unroll
    for (int i = 0; i < 4; ++i)
      af[i] = *(const bf16x8*)&As[bb][(wr * 64 + i * 16 + lr) * 32 + quad * 8];
#pragma unroll
    for (int j = 0; j < 4; ++j)
      bfr[j] = *(const bf16x8*)&Bs[bb][(wc * 64 + j * 16 + lr) * 32 + quad * 8];
#pragma unroll
    for (int i = 0; i < 4; ++i)
#pragma unroll
      for (int j = 0; j < 4; ++j)
        acc[i][j] = __builtin_amdgcn_mfma_f32_16x16x32_bf16(af[i], bfr[j], acc[i][j], 0, 0, 0);
  }

  // Epilogue: wave-uniform (which, head) from column block.
  const int col0 = n0 + wc * 64;
  const int which = col0 >> 10;             // 0=q, 1=k, 2=v
  const int h = (col0 & 1023) >> 6;
  const float tsc = tau[h] * 0.125f * LOG2E;
  unsigned short* dst = (which == 0) ? Qh : (which == 1) ? Kh : Vh;

#pragma unroll
  for (int i = 0; i < 4; ++i)
#pragma unroll
    for (int r = 0; r < 4; ++r) {
      const int s = m0 + wr * 64 + i * 16 + quad * 4 + r;   // global row 0..4095
      unsigned short* ar =
          dst + (((size_t)((s >> 11) * NHEAD + h)) * SEQ + (s & 2047)) * DHEAD;
      float scale;
      if (which == 2) {
        scale = 1.0f;
      } else {
        float ss = 0.f;
#pragma unroll
        for (int j = 0; j < 4; ++j) ss += acc[i][j][r] * acc[i][j][r];
        ss += __shfl_xor(ss, 1, 16);
        ss += __shfl_xor(ss, 2, 16);
        ss += __shfl_xor(ss, 4, 16);
        ss += __shfl_xor(ss, 8, 16);
        scale = 1.0f / (sqrtf(ss) + EPS);
        if (which == 0) scale *= tsc;       // tau/sqrt(DH) * log2e into Q
      }
#pragma unroll
      for (int j = 0; j < 4; ++j) ar[j * 16 + lr] = f2bf(acc[i][j][r] * scale);
    }
}

// ---------------------------------------------------------------------------
// V transpose: Vh [BH][S][DH] -> Vt [BH][DH][S]. 64x64 LDS tiles.
// ---------------------------------------------------------------------------
__global__ __launch_bounds__(256) void vtrans_kernel(
    const unsigned short* __restrict__ Vh, unsigned short* __restrict__ Vt) {
  __shared__ unsigned short tile[64][72];
  const int bh = blockIdx.x;
  const int s0 = blockIdx.y * 64;
  const int t = threadIdx.x;
  const int sr = t >> 2;          // 0..63
  const int dc = (t & 3) * 16;    // 0,16,32,48
  const unsigned short* src = Vh + ((size_t)bh * SEQ + s0 + sr) * DHEAD + dc;
  *(bf16x8*)&tile[sr][dc]     = *(const bf16x8*)(src);
  *(bf16x8*)&tile[sr][dc + 8] = *(const bf16x8*)(src + 8);
  __syncthreads();
  const int dr = t >> 2;          // 0..63 (d row)
  const int sc = (t & 3) * 16;    // s chunk
  unsigned short buf[16];
#pragma unroll
  for (int i = 0; i < 16; ++i) buf[i] = tile[sc + i][dr];
  unsigned short* dst = Vt + ((size_t)bh * DHEAD + dr) * SEQ + s0 + sc;
  *(bf16x8*)dst       = *(const bf16x8*)buf;
  *(bf16x8*)(dst + 8) = *(const bf16x8*)(buf + 8);
}

// ---------------------------------------------------------------------------
// Causal flash attention, bf16 MFMA — R10: EQUAL-WORK 512-thread blocks.
// grid = 256: bh = idx&31, j = idx>>5 (0..7). Each block processes q-block
// qA = 15-j then qB = j SEQUENTIALLY: 2(16-j) + 2(j+1) = 34 steps for every
// block -> perfectly flat 8-wave/CU residency, no tail (R9's 2-block pairing
// equalized work but not concurrency: light block died after 1 step leaving
// its CU at 4 waves -> measured occupancy 13.5%). 8 waves, each owns ONE
// 16-row q-tile per phase. Phase switch mid-loop with next tile already
// prefetched (no bubble); phase-A epilogue inlined at the switch.
// Per 64-key step/wave: 8 QK MFMAs (swapped S^T = K*Q^T), fixed-max exp2
// softmax (no subtract), packed-b64 P writes, 8 PV MFMAs from LDS V^T.
// ---------------------------------------------------------------------------
#define PLS 72   // P row stride in shorts (144 B)

__global__ __launch_bounds__(512, 1) void attn_kernel(
    const unsigned short* __restrict__ Qh, const unsigned short* __restrict__ Kh,
    const unsigned short* __restrict__ Vt, unsigned short* __restrict__ attnb) {
  __shared__ unsigned short Ks[2][2][64 * 32];   // [buf][d-half][key*32 + d']
  __shared__ unsigned short Vs[2][2][64 * 32];   // [buf][key-half][d*32 + key']
  __shared__ unsigned short Pl[8][16 * PLS];     // [wave][q*PLS + key]

  const int idx = blockIdx.x;
  const int bh = idx & 31;
  const int j = idx >> 5;               // 0..7
  const int qA = 15 - j, qB = j;        // steps: 2(qA+1) + 2(qB+1) = 34
  const int b = bh >> 4;
  const int h = bh & 15;
  const int t = threadIdx.x;
  const int w = t >> 6;                 // 0..7
  const int lane = t & 63;
  const int quad = lane >> 4;
  const int lr = lane & 15;

  const unsigned short* Qp = Qh + (size_t)bh * SEQ * DHEAD;
  const unsigned short* Kp = Kh + (size_t)bh * SEQ * DHEAD;
  const unsigned short* Vp = Vt + (size_t)bh * DHEAD * SEQ;
  unsigned short* Pw = &Pl[w][0];

  // staging: 16 async_ld16 per step (8 K + 8 V), wave w issues 2.
  const int srow = lane >> 2;        // 0..15
  const int scol = (lane & 3) * 8;   // 16B segment within 32-short row
  const int f0 = w * 2;

  auto stage = [&](int k0, int bb) {
#pragma unroll
    for (int i = 0; i < 2; ++i) {
      const int fi = f0 + i;
      if (fi < 8) {   // K half-tiles: [key][32 d']
        const int hh = fi >> 2, seg = fi & 3;
        async_ld16(Kp + (size_t)(k0 + seg * 16 + srow) * DHEAD + hh * 32 + scol,
                   &Ks[bb][hh][seg * 512]);
      } else {        // V^T half-tiles: [d][32 key']
        const int g = fi - 8;
        const int cc = g >> 2, seg = g & 3;
        async_ld16(Vp + (size_t)(seg * 16 + srow) * SEQ + k0 + cc * 32 + scol,
                   &Vs[bb][cc][seg * 512]);
      }
    }
  };

  // Q fragments (B-operand) for both phases: lane holds Q[qb+lr][...]
  bf16x8 aq[2][2];
  {
    const unsigned short* qrA = Qp + (size_t)(qA * 128 + w * 16 + lr) * DHEAD;
    const unsigned short* qrB = Qp + (size_t)(qB * 128 + w * 16 + lr) * DHEAD;
    aq[0][0] = *(const bf16x8*)(qrA + quad * 8);
    aq[0][1] = *(const bf16x8*)(qrA + 32 + quad * 8);
    aq[1][0] = *(const bf16x8*)(qrB + quad * 8);
    aq[1][1] = *(const bf16x8*)(qrB + 32 + quad * 8);
  }

  const f32x4 zero4 = {0.f, 0.f, 0.f, 0.f};
  f32x4 o[4];
  o[0] = o[1] = o[2] = o[3] = zero4;
  float l_ = 0.f;

  // epilogue: per-lane l is for q=lr; reduce across quads; broadcast 1/l to
  // the C-layout rows (q=quad*4+r); write bf16.
  auto epilogue = [&](int qbt) {
    float lt = l_;
    lt += __shfl_xor(lt, 16, 64);
    lt += __shfl_xor(lt, 32, 64);
    const float inv = 1.0f / lt;          // valid for q = lr
#pragma unroll
    for (int r = 0; r < 4; ++r) {
      const float invr = __shfl(inv, quad * 4 + r, 16);
      unsigned short* ar =
          attnb + ((size_t)(b * SEQ + qbt + quad * 4 + r)) * DMODEL + h * DHEAD;
#pragma unroll
      for (int nt = 0; nt < 4; ++nt) ar[nt * 16 + lr] = f2bf(o[nt][r] * invr);
    }
  };

  const int sA = 2 * (qA + 1);
  const int total = sA + 2 * (qB + 1);

  stage(0, 0);
  int bb = 0;
  int ph = 0;
  int q0 = qA * 128;
  for (int s = 0; s < total; ++s, bb ^= 1) {
    const int k0 = (s < sA ? s : s - sA) * 64;
    __syncthreads();                       // buf bb staged; prev reads done
    const int ns = s + 1;
    if (ns < total) stage((ns < sA ? ns : ns - sA) * 64, bb ^ 1);

    const int qb = q0 + w * 16;
    if (k0 <= qb + 15) {                   // wave-uniform: tile has live keys
      // --- QK^T (swapped): A = K frag, B = Q frag; chain two 32-d halves
      f32x4 c[4];
#pragma unroll
      for (int kt = 0; kt < 4; ++kt) {
        const bf16x8 kf0 = *(const bf16x8*)&Ks[bb][0][(kt * 16 + lr) * 32 + quad * 8];
        const bf16x8 kf1 = *(const bf16x8*)&Ks[bb][1][(kt * 16 + lr) * 32 + quad * 8];
        f32x4 tt = __builtin_amdgcn_mfma_f32_16x16x32_bf16(kf0, aq[ph][0], zero4, 0, 0, 0);
        c[kt] = __builtin_amdgcn_mfma_f32_16x16x32_bf16(kf1, aq[ph][1], tt, 0, 0, 0);
      }

      // --- fixed-max exp2 softmax, packed-b64 P writes, per-lane l
      float ps = 0.f;
      if (k0 + 63 > qb) {                  // diagonal-crossing step: mask
        const int qrow = qb + lr;
#pragma unroll
        for (int kt = 0; kt < 4; ++kt) {
          float p[4];
#pragma unroll
          for (int r = 0; r < 4; ++r) {
            const int key = k0 + kt * 16 + quad * 4 + r;
            p[r] = (key <= qrow) ? exp2f(c[kt][r]) : 0.f;
            ps += p[r];
          }
          const unsigned lo = pkbf(p[0], p[1]);
          const unsigned hi = pkbf(p[2], p[3]);
          *(unsigned long long*)&Pw[lr * PLS + kt * 16 + quad * 4] =
              ((unsigned long long)hi << 32) | lo;
        }
      } else {
#pragma unroll
        for (int kt = 0; kt < 4; ++kt) {
          float p[4];
#pragma unroll
          for (int r = 0; r < 4; ++r) {
            p[r] = exp2f(c[kt][r]);
            ps += p[r];
          }
          const unsigned lo = pkbf(p[0], p[1]);
          const unsigned hi = pkbf(p[2], p[3]);
          *(unsigned long long*)&Pw[lr * PLS + kt * 16 + quad * 4] =
              ((unsigned long long)hi << 32) | lo;
        }
      }
      l_ += ps;

      // --- PV: A = P readback (row lr, contiguous keys), B = V^T frags
#pragma unroll
      for (int c2 = 0; c2 < 2; ++c2) {
        const bf16x8 pa = *(const bf16x8*)&Pw[lr * PLS + c2 * 32 + quad * 8];
#pragma unroll
        for (int nt = 0; nt < 4; ++nt) {
          const bf16x8 vb = *(const bf16x8*)&Vs[bb][c2][(nt * 16 + lr) * 32 + quad * 8];
          o[nt] = __builtin_amdgcn_mfma_f32_16x16x32_bf16(pa, vb, o[nt], 0, 0, 0);
        }
      }
    }

    if (s == sA - 1) {                     // phase A done: write, reset, switch
      epilogue(qA * 128 + w * 16);
      o[0] = o[1] = o[2] = o[3] = zero4;
      l_ = 0.f;
      ph = 1;
      q0 = qB * 128;
    }
  }
  epilogue(qB * 128 + w * 16);
}

// ---------------------------------------------------------------------------
// Launch
// ---------------------------------------------------------------------------
extern "C" void kernel_launch(void* const* d_in, const int* in_sizes, int n_in,
                              void* d_out, int out_size, void* d_ws, size_t ws_size,
                              hipStream_t stream) {
  const float* x    = (const float*)d_in[0];
  // d_in[1]: fixed causal tril mask -> handled analytically, never read.
  const float* Wqkv = (const float*)d_in[2];
  const float* Wo   = (const float*)d_in[3];
  const float* tau  = (const float*)d_in[4];
  float* out = (float*)d_out;

  // workspace layout (~50 MB): no f32 qkv buffer (norm fused in GEMM1)
  unsigned short* attnb = (unsigned short*)d_ws;                      // bf16 [B,S,D]
  unsigned short* Qh = attnb + (size_t)BATCH * SEQ * DMODEL;          // bf16 [B,H,S,DH]
  unsigned short* Kh = Qh + (size_t)BATCH * NHEAD * SEQ * DHEAD;
  unsigned short* Vh = Kh + (size_t)BATCH * NHEAD * SEQ * DHEAD;
  unsigned short* Xb = Vh + (size_t)BATCH * NHEAD * SEQ * DHEAD;      // bf16 [B*S][D]
  unsigned short* Wqkv_t = Xb + (size_t)BATCH * SEQ * DMODEL;         // bf16 [3D][D]
  unsigned short* Wo_t = Wqkv_t + (size_t)DMODEL * QKV_COLS;          // bf16 [D][D]
  unsigned short* Vt = Wo_t + (size_t)DMODEL * DMODEL;                // bf16 [BH][DH][S]

  const int M = BATCH * SEQ;  // 4096

  // 0) prep: bf16 conversion + fused weight transposes
  convert_x_kernel<<<(M * DMODEL) / (256 * 4), 256, 0, stream>>>(x, Xb);
  transpose_w2_kernel<<<dim3(128, 32), dim3(32, 8), 0, stream>>>(
      Wqkv, Wqkv_t, Wo, Wo_t);

  // 1) GEMM1 + fused qk-norm -> Qh/Kh/Vh bf16 head-major
  qkv_gemm_norm_kernel<<<dim3(QKV_COLS / 128, M / 128), 256, 0, stream>>>(
      Xb, Wqkv_t, tau, Qh, Kh, Vh);

  // 2) V -> V^T [BH][DH][S]
  vtrans_kernel<<<dim3(BATCH * NHEAD, SEQ / 64), 256, 0, stream>>>(Vh, Vt);

  // 3) causal MFMA flash attention -> attnb bf16 [B,S,D]
  //    grid 256: every block = exactly 34 steps (equal work, flat occupancy)
  attn_kernel<<<dim3(256), 512, 0, stream>>>(Qh, Kh, Vt, attnb);

  // 4) out = attn @ Wo  (M=4096, N=1024, K=1024), f32 out
  sgemm_bf16_kernel<<<dim3(DMODEL / 128, M / 128), 256, 0, stream>>>(
      attnb, Wo_t, out, M, DMODEL, DMODEL);
}

// Round 11
// 204.178 us; speedup vs baseline: 2.1025x; 2.1025x over previous
//
#include <hip/hip_runtime.h>
#include <math.h>

// Problem constants (from reference): B=2, S=2048, D=1024, H=16, DH=64
#define BATCH 2
#define SEQ 2048
#define DMODEL 1024
#define NHEAD 16
#define DHEAD 64
#define QKV_COLS (3 * DMODEL)          // 3072
#define EPS 1e-8f
#define LOG2E 1.44269504f

typedef short bf16x8 __attribute__((ext_vector_type(8)));   // 8 bf16 (4 VGPRs)
typedef float f32x4 __attribute__((ext_vector_type(4)));    // 4 fp32 acc

// round-to-nearest-even float -> bf16 (as raw ushort)
static __device__ __forceinline__ unsigned short f2bf(float x) {
  unsigned u = __float_as_uint(x);
  u += 0x7fffu + ((u >> 16) & 1u);
  return (unsigned short)(u >> 16);
}

// pack two f32 -> (bf16(hi)<<16)|bf16(lo) in 3 VALU (round-half-up + v_perm)
static __device__ __forceinline__ unsigned pkbf(float lo, float hi) {
  const unsigned ul = __float_as_uint(lo) + 0x8000u;
  const unsigned uh = __float_as_uint(hi) + 0x8000u;
  return __builtin_amdgcn_perm(uh, ul, 0x07060302);  // [uh.hi16 | ul.hi16]
}

// async global->LDS, 16 B per lane (global_load_lds_dwordx4).
// LDS dest: wave-uniform base + lane*16 (m104/m108).
static __device__ __forceinline__ void async_ld16(const unsigned short* g,
                                                  unsigned short* l) {
  __builtin_amdgcn_global_load_lds(
      (const __attribute__((address_space(1))) void*)g,
      (__attribute__((address_space(3))) void*)(unsigned int)(unsigned long long)l,
      16, 0, 0);
}

// ---------------------------------------------------------------------------
// Prep 1: x f32 [M][K] -> bf16 same layout. 4 floats/thread.
// ---------------------------------------------------------------------------
__global__ __launch_bounds__(256) void convert_x_kernel(
    const float* __restrict__ x, unsigned short* __restrict__ xb) {
  const size_t i = ((size_t)blockIdx.x * 256 + threadIdx.x) * 4;
  const float4 a = *(const float4*)(x + i);
  ushort4 r;
  r.x = f2bf(a.x); r.y = f2bf(a.y); r.z = f2bf(a.z); r.w = f2bf(a.w);
  *(ushort4*)(xb + i) = r;
}

// ---------------------------------------------------------------------------
// Prep 2 (fused): both weight transposes in one launch.
// ---------------------------------------------------------------------------
__global__ __launch_bounds__(256) void transpose_w2_kernel(
    const float* __restrict__ W0, unsigned short* __restrict__ Wt0,
    const float* __restrict__ W1, unsigned short* __restrict__ Wt1) {
  __shared__ float tile[32][33];
  const int bx = blockIdx.x;
  const float* W;
  unsigned short* Wt;
  int N, n0;
  if (bx < 96) { W = W0; Wt = Wt0; N = QKV_COLS; n0 = bx * 32; }
  else         { W = W1; Wt = Wt1; N = DMODEL;   n0 = (bx - 96) * 32; }
  const int K = DMODEL;
  const int k0 = blockIdx.y * 32;
  const int tx = threadIdx.x, ty = threadIdx.y;
#pragma unroll
  for (int i = 0; i < 4; ++i)
    tile[ty + i * 8][tx] = W[(size_t)(k0 + ty + i * 8) * N + n0 + tx];
  __syncthreads();
#pragma unroll
  for (int i = 0; i < 4; ++i)
    Wt[(size_t)(n0 + ty + i * 8) * K + k0 + tx] = f2bf(tile[tx][ty + i * 8]);
}

// ---------------------------------------------------------------------------
// bf16 MFMA GEMM, double-buffered staging. C = A @ Bt^T. Used for GEMM2.
// ---------------------------------------------------------------------------
__global__ __launch_bounds__(256) void sgemm_bf16_kernel(
    const unsigned short* __restrict__ A, const unsigned short* __restrict__ Bt,
    float* __restrict__ C, int M, int N, int K) {
  __shared__ unsigned short As[2][128 * 32];   // [buf][m][k]
  __shared__ unsigned short Bs[2][128 * 32];   // [buf][n][k]

  const int t = threadIdx.x;
  const int w = t >> 6;
  const int lane = t & 63;
  const int quad = lane >> 4;
  const int lr = lane & 15;
  const int wr = w >> 1, wc = w & 1;
  const int m0 = blockIdx.y * 128;
  const int n0 = blockIdx.x * 128;

  const int srow = w * 32 + (lane >> 2);
  const int scol = (lane & 3) * 8;
  const unsigned short* ga = A + (size_t)(m0 + srow) * K + scol;
  const unsigned short* gb = Bt + (size_t)(n0 + srow) * K + scol;

  auto stage = [&](int k0, int bb) {
#pragma unroll
    for (int i = 0; i < 2; ++i) {
      async_ld16(ga + (size_t)(i * 16) * K + k0, &As[bb][(w * 32 + i * 16) * 32]);
      async_ld16(gb + (size_t)(i * 16) * K + k0, &Bs[bb][(w * 32 + i * 16) * 32]);
    }
  };

  f32x4 acc[4][4];
  const f32x4 zero4 = {0.f, 0.f, 0.f, 0.f};
#pragma unroll
  for (int i = 0; i < 4; ++i)
#pragma unroll
    for (int j = 0; j < 4; ++j) acc[i][j] = zero4;

  stage(0, 0);
  int bb = 0;
  for (int k0 = 0; k0 < K; k0 += 32, bb ^= 1) {
    __syncthreads();
    if (k0 + 32 < K) stage(k0 + 32, bb ^ 1);

    bf16x8 af[4], bfr[4];
#pragma unroll
    for (int i = 0; i < 4; ++i)
      af[i] = *(const bf16x8*)&As[bb][(wr * 64 + i * 16 + lr) * 32 + quad * 8];
#pragma unroll
    for (int j = 0; j < 4; ++j)
      bfr[j] = *(const bf16x8*)&Bs[bb][(wc * 64 + j * 16 + lr) * 32 + quad * 8];
#pragma unroll
    for (int i = 0; i < 4; ++i)
#pragma unroll
      for (int j = 0; j < 4; ++j)
        acc[i][j] = __builtin_amdgcn_mfma_f32_16x16x32_bf16(af[i], bfr[j], acc[i][j], 0, 0, 0);
  }

#pragma unroll
  for (int i = 0; i < 4; ++i)
#pragma unroll
    for (int r = 0; r < 4; ++r) {
      float* c = C + (size_t)(m0 + wr * 64 + i * 16 + quad * 4 + r) * N + n0 + wc * 64 + lr;
#pragma unroll
      for (int j = 0; j < 4; ++j) c[j * 16] = acc[i][j][r];
    }
}

// ---------------------------------------------------------------------------
// GEMM1 + fused qk-norm, double-buffered. Writes bf16 Qh/Kh/Vh [B,H,S,DH].
// ---------------------------------------------------------------------------
__global__ __launch_bounds__(256) void qkv_gemm_norm_kernel(
    const unsigned short* __restrict__ A, const unsigned short* __restrict__ Bt,
    const float* __restrict__ tau,
    unsigned short* __restrict__ Qh, unsigned short* __restrict__ Kh,
    unsigned short* __restrict__ Vh) {
  __shared__ unsigned short As[2][128 * 32];
  __shared__ unsigned short Bs[2][128 * 32];

  const int K = DMODEL, N = QKV_COLS;
  const int t = threadIdx.x;
  const int w = t >> 6;
  const int lane = t & 63;
  const int quad = lane >> 4;
  const int lr = lane & 15;
  const int wr = w >> 1, wc = w & 1;
  const int m0 = blockIdx.y * 128;
  const int n0 = blockIdx.x * 128;

  const int srow = w * 32 + (lane >> 2);
  const int scol = (lane & 3) * 8;
  const unsigned short* ga = A + (size_t)(m0 + srow) * K + scol;
  const unsigned short* gb = Bt + (size_t)(n0 + srow) * K + scol;

  auto stage = [&](int k0, int bb) {
#pragma unroll
    for (int i = 0; i < 2; ++i) {
      async_ld16(ga + (size_t)(i * 16) * K + k0, &As[bb][(w * 32 + i * 16) * 32]);
      async_ld16(gb + (size_t)(i * 16) * K + k0, &Bs[bb][(w * 32 + i * 16) * 32]);
    }
  };

  f32x4 acc[4][4];
  const f32x4 zero4 = {0.f, 0.f, 0.f, 0.f};
#pragma unroll
  for (int i = 0; i < 4; ++i)
#pragma unroll
    for (int j = 0; j < 4; ++j) acc[i][j] = zero4;

  stage(0, 0);
  int bb = 0;
  for (int k0 = 0; k0 < K; k0 += 32, bb ^= 1) {
    __syncthreads();
    if (k0 + 32 < K) stage(k0 + 32, bb ^ 1);

    bf16x8 af[4], bfr[4];
#pragma unroll
    for (int i = 0; i < 4; ++i)
      af[i] = *(const bf16x8*)&As[bb][(wr * 64 + i * 16 + lr) * 32 + quad * 8];
#pragma unroll
    for (int j = 0; j < 4; ++j)
      bfr[j] = *(const bf16x8*)&Bs[bb][(wc * 64 + j * 16 + lr) * 32 + quad * 8];
#pragma unroll
    for (int i = 0; i < 4; ++i)
#pragma unroll
      for (int j = 0; j < 4; ++j)
        acc[i][j] = __builtin_amdgcn_mfma_f32_16x16x32_bf16(af[i], bfr[j], acc[i][j], 0, 0, 0);
  }

  // Epilogue: wave-uniform (which, head) from column block.
  const int col0 = n0 + wc * 64;
  const int which = col0 >> 10;             // 0=q, 1=k, 2=v
  const int h = (col0 & 1023) >> 6;
  const float tsc = tau[h] * 0.125f * LOG2E;
  unsigned short* dst = (which == 0) ? Qh : (which == 1) ? Kh : Vh;

#pragma unroll
  for (int i = 0; i < 4; ++i)
#pragma unroll
    for (int r = 0; r < 4; ++r) {
      const int s = m0 + wr * 64 + i * 16 + quad * 4 + r;   // global row 0..4095
      unsigned short* ar =
          dst + (((size_t)((s >> 11) * NHEAD + h)) * SEQ + (s & 2047)) * DHEAD;
      float scale;
      if (which == 2) {
        scale = 1.0f;
      } else {
        float ss = 0.f;
#pragma unroll
        for (int j = 0; j < 4; ++j) ss += acc[i][j][r] * acc[i][j][r];
        ss += __shfl_xor(ss, 1, 16);
        ss += __shfl_xor(ss, 2, 16);
        ss += __shfl_xor(ss, 4, 16);
        ss += __shfl_xor(ss, 8, 16);
        scale = 1.0f / (sqrtf(ss) + EPS);
        if (which == 0) scale *= tsc;       // tau/sqrt(DH) * log2e into Q
      }
#pragma unroll
      for (int j = 0; j < 4; ++j) ar[j * 16 + lr] = f2bf(acc[i][j][r] * scale);
    }
}

// ---------------------------------------------------------------------------
// V transpose: Vh [BH][S][DH] -> Vt [BH][DH][S]. 64x64 LDS tiles.
// ---------------------------------------------------------------------------
__global__ __launch_bounds__(256) void vtrans_kernel(
    const unsigned short* __restrict__ Vh, unsigned short* __restrict__ Vt) {
  __shared__ unsigned short tile[64][72];
  const int bh = blockIdx.x;
  const int s0 = blockIdx.y * 64;
  const int t = threadIdx.x;
  const int sr = t >> 2;          // 0..63
  const int dc = (t & 3) * 16;    // 0,16,32,48
  const unsigned short* src = Vh + ((size_t)bh * SEQ + s0 + sr) * DHEAD + dc;
  *(bf16x8*)&tile[sr][dc]     = *(const bf16x8*)(src);
  *(bf16x8*)&tile[sr][dc + 8] = *(const bf16x8*)(src + 8);
  __syncthreads();
  const int dr = t >> 2;          // 0..63 (d row)
  const int sc = (t & 3) * 16;    // s chunk
  unsigned short buf[16];
#pragma unroll
  for (int i = 0; i < 16; ++i) buf[i] = tile[sc + i][dr];
  unsigned short* dst = Vt + ((size_t)bh * DHEAD + dr) * SEQ + s0 + sc;
  *(bf16x8*)dst       = *(const bf16x8*)buf;
  *(bf16x8*)(dst + 8) = *(const bf16x8*)(buf + 8);
}

// ---------------------------------------------------------------------------
// Causal flash attention — R11: equal-work 256-thread blocks, 2 blocks/CU.
// R10 lesson: one 512-thread mega-block per CU = single barrier domain ->
// whole-CU stalls at every step barrier (280 us). R11 keeps R9's proven
// 4-wave / 41 KB block (2 independent barrier domains per CU overlap each
// other's stalls) and fixes only the balance: block (bh, i) processes
// q-64-block (31-i) then (i) SEQUENTIALLY -> (31-i+1)+(i+1) = 33 steps of
// 64 keys for EVERY block; grid 512 = 2 resident blocks/CU, flat occupancy,
// zero tail. Wave w owns q rows q0 + w*16..+15 in each phase; every wave is
// active on every step of its phase (no alive-guards); mask only on each
// phase's final (diagonal) step.
// Per 64-key wave-step: 8 QK MFMAs (swapped S^T = K*Q^T), fixed-max exp2
// softmax (no subtract), packed-b64 P write, 8 PV MFMAs from LDS V^T tile.
// K/V staged via double-buffered global_load_lds (16 instrs/step, 4/wave).
// ---------------------------------------------------------------------------
#define PLS 72   // P row stride in shorts (144 B)

__global__ __launch_bounds__(256, 2) void attn_kernel(
    const unsigned short* __restrict__ Qh, const unsigned short* __restrict__ Kh,
    const unsigned short* __restrict__ Vt, unsigned short* __restrict__ attnb) {
  __shared__ unsigned short Ks[2][2][64 * 32];   // [buf][d-half][key*32 + d']
  __shared__ unsigned short Vs[2][2][64 * 32];   // [buf][key-half][d*32 + key']
  __shared__ unsigned short Pl[4][16 * PLS];     // [wave][q*PLS + key]

  const int idx = blockIdx.x;
  const int bh = idx & 31;
  const int i = idx >> 5;               // 0..15
  const int qA = 31 - i, qB = i;        // q-64-block indices; steps = 33 total
  const int b = bh >> 4;
  const int h = bh & 15;
  const int t = threadIdx.x;
  const int w = t >> 6;
  const int lane = t & 63;
  const int quad = lane >> 4;
  const int lr = lane & 15;

  const unsigned short* Qp = Qh + (size_t)bh * SEQ * DHEAD;
  const unsigned short* Kp = Kh + (size_t)bh * SEQ * DHEAD;
  const unsigned short* Vp = Vt + (size_t)bh * DHEAD * SEQ;
  unsigned short* Pw = &Pl[w][0];

  // staging: 16 async_ld16 per step (8 K + 8 V), wave w issues 4 (R9 pattern).
  const int srow = lane >> 2;        // 0..15
  const int scol = (lane & 3) * 8;   // 16B segment within 32-short row
  const int f0 = w * 4;

  auto stage = [&](int k0, int bb) {
#pragma unroll
    for (int ii = 0; ii < 4; ++ii) {
      const int fi = f0 + ii;
      if (fi < 8) {   // K half-tiles: [key][32 d']
        const int hh = fi >> 2, seg = fi & 3;
        async_ld16(Kp + (size_t)(k0 + seg * 16 + srow) * DHEAD + hh * 32 + scol,
                   &Ks[bb][hh][seg * 512]);
      } else {        // V^T half-tiles: [d][32 key']
        const int g = fi - 8;
        const int cc = g >> 2, seg = g & 3;
        async_ld16(Vp + (size_t)(seg * 16 + srow) * SEQ + k0 + cc * 32 + scol,
                   &Vs[bb][cc][seg * 512]);
      }
    }
  };

  const f32x4 zero4 = {0.f, 0.f, 0.f, 0.f};
  f32x4 o[4];
  o[0] = o[1] = o[2] = o[3] = zero4;
  float l_ = 0.f;

  // one 64-key step for q-tile at qb, reading staged buffer bb
#define STEP(aq0_, aq1_, qb_, k0_, bb_, msk_)                                 \
  do {                                                                        \
    f32x4 c[4];                                                               \
    _Pragma("unroll")                                                         \
    for (int kt = 0; kt < 4; ++kt) {                                          \
      const bf16x8 kf0 = *(const bf16x8*)&Ks[bb_][0][(kt * 16 + lr) * 32 + quad * 8]; \
      const bf16x8 kf1 = *(const bf16x8*)&Ks[bb_][1][(kt * 16 + lr) * 32 + quad * 8]; \
      f32x4 tt = __builtin_amdgcn_mfma_f32_16x16x32_bf16(kf0, aq0_, zero4, 0, 0, 0);  \
      c[kt] = __builtin_amdgcn_mfma_f32_16x16x32_bf16(kf1, aq1_, tt, 0, 0, 0);        \
    }                                                                         \
    float ps = 0.f;                                                           \
    if (msk_) {                                                               \
      const int qrow = (qb_) + lr;                                            \
      _Pragma("unroll")                                                       \
      for (int kt = 0; kt < 4; ++kt) {                                        \
        float p[4];                                                           \
        _Pragma("unroll")                                                     \
        for (int r = 0; r < 4; ++r) {                                         \
          const int key = (k0_) + kt * 16 + quad * 4 + r;                     \
          p[r] = (key <= qrow) ? exp2f(c[kt][r]) : 0.f;                       \
          ps += p[r];                                                         \
        }                                                                     \
        const unsigned lo = pkbf(p[0], p[1]);                                 \
        const unsigned hi = pkbf(p[2], p[3]);                                 \
        *(unsigned long long*)&Pw[lr * PLS + kt * 16 + quad * 4] =            \
            ((unsigned long long)hi << 32) | lo;                              \
      }                                                                       \
    } else {                                                                  \
      _Pragma("unroll")                                                       \
      for (int kt = 0; kt < 4; ++kt) {                                        \
        float p[4];                                                           \
        _Pragma("unroll")                                                     \
        for (int r = 0; r < 4; ++r) {                                         \
          p[r] = exp2f(c[kt][r]);                                             \
          ps += p[r];                                                         \
        }                                                                     \
        const unsigned lo = pkbf(p[0], p[1]);                                 \
        const unsigned hi = pkbf(p[2], p[3]);                                 \
        *(unsigned long long*)&Pw[lr * PLS + kt * 16 + quad * 4] =            \
            ((unsigned long long)hi << 32) | lo;                              \
      }                                                                       \
    }                                                                         \
    l_ += ps;                                                                 \
    _Pragma("unroll")                                                         \
    for (int c2 = 0; c2 < 2; ++c2) {                                          \
      const bf16x8 pa = *(const bf16x8*)&Pw[lr * PLS + c2 * 32 + quad * 8];   \
      _Pragma("unroll")                                                       \
      for (int nt = 0; nt < 4; ++nt) {                                        \
        const bf16x8 vb = *(const bf16x8*)&Vs[bb_][c2][(nt * 16 + lr) * 32 + quad * 8]; \
        o[nt] = __builtin_amdgcn_mfma_f32_16x16x32_bf16(pa, vb, o[nt], 0, 0, 0);        \
      }                                                                       \
    }                                                                         \
  } while (0)

  // epilogue: per-lane l is for q=lr; reduce across quads; broadcast 1/l to
  // the C-layout rows (q=quad*4+r); write bf16; reset state.
  auto epilogue = [&](int qbt) {
    float lt = l_;
    lt += __shfl_xor(lt, 16, 64);
    lt += __shfl_xor(lt, 32, 64);
    const float inv = 1.0f / lt;          // valid for q = lr
#pragma unroll
    for (int r = 0; r < 4; ++r) {
      const float invr = __shfl(inv, quad * 4 + r, 16);
      unsigned short* ar =
          attnb + ((size_t)(b * SEQ + qbt + quad * 4 + r)) * DMODEL + h * DHEAD;
#pragma unroll
      for (int nt = 0; nt < 4; ++nt) ar[nt * 16 + lr] = f2bf(o[nt][r] * invr);
    }
  };

  // Q fragments for both phases (B-operand: lane holds Q[qb+lr][...]).
  const int qbA = qA * 64 + w * 16;
  const int qbB = qB * 64 + w * 16;
  const unsigned short* qrA = Qp + (size_t)(qbA + lr) * DHEAD;
  const unsigned short* qrB = Qp + (size_t)(qbB + lr) * DHEAD;
  const bf16x8 aqA0 = *(const bf16x8*)(qrA + quad * 8);
  const bf16x8 aqA1 = *(const bf16x8*)(qrA + 32 + quad * 8);
  const bf16x8 aqB0 = *(const bf16x8*)(qrB + quad * 8);
  const bf16x8 aqB1 = *(const bf16x8*)(qrB + 32 + quad * 8);

  const int kendA = qA * 64;   // last step's k0 (diagonal step)
  const int kendB = qB * 64;

  stage(0, 0);
  int bb = 0;

  // --- phase A: q-64-block qA, keys 0..kendA+63 ---
  for (int k0 = 0; k0 <= kendA; k0 += 64, bb ^= 1) {
    __syncthreads();                       // buf bb staged; prev reads done
    // prefetch: next A tile, or phase B's first tile (k=0) on the last step
    stage(k0 < kendA ? k0 + 64 : 0, bb ^ 1);
    STEP(aqA0, aqA1, qbA, k0, bb, (k0 == kendA));
  }
  epilogue(qbA);
  o[0] = o[1] = o[2] = o[3] = zero4;
  l_ = 0.f;

  // --- phase B: q-64-block qB, keys 0..kendB+63 ---
  for (int k0 = 0; k0 <= kendB; k0 += 64, bb ^= 1) {
    __syncthreads();
    if (k0 < kendB) stage(k0 + 64, bb ^ 1);
    STEP(aqB0, aqB1, qbB, k0, bb, (k0 == kendB));
  }
  epilogue(qbB);
#undef STEP
}

// ---------------------------------------------------------------------------
// Launch
// ---------------------------------------------------------------------------
extern "C" void kernel_launch(void* const* d_in, const int* in_sizes, int n_in,
                              void* d_out, int out_size, void* d_ws, size_t ws_size,
                              hipStream_t stream) {
  const float* x    = (const float*)d_in[0];
  // d_in[1]: fixed causal tril mask -> handled analytically, never read.
  const float* Wqkv = (const float*)d_in[2];
  const float* Wo   = (const float*)d_in[3];
  const float* tau  = (const float*)d_in[4];
  float* out = (float*)d_out;

  // workspace layout (~50 MB): no f32 qkv buffer (norm fused in GEMM1)
  unsigned short* attnb = (unsigned short*)d_ws;                      // bf16 [B,S,D]
  unsigned short* Qh = attnb + (size_t)BATCH * SEQ * DMODEL;          // bf16 [B,H,S,DH]
  unsigned short* Kh = Qh + (size_t)BATCH * NHEAD * SEQ * DHEAD;
  unsigned short* Vh = Kh + (size_t)BATCH * NHEAD * SEQ * DHEAD;
  unsigned short* Xb = Vh + (size_t)BATCH * NHEAD * SEQ * DHEAD;      // bf16 [B*S][D]
  unsigned short* Wqkv_t = Xb + (size_t)BATCH * SEQ * DMODEL;         // bf16 [3D][D]
  unsigned short* Wo_t = Wqkv_t + (size_t)DMODEL * QKV_COLS;          // bf16 [D][D]
  unsigned short* Vt = Wo_t + (size_t)DMODEL * DMODEL;                // bf16 [BH][DH][S]

  const int M = BATCH * SEQ;  // 4096

  // 0) prep: bf16 conversion + fused weight transposes
  convert_x_kernel<<<(M * DMODEL) / (256 * 4), 256, 0, stream>>>(x, Xb);
  transpose_w2_kernel<<<dim3(128, 32), dim3(32, 8), 0, stream>>>(
      Wqkv, Wqkv_t, Wo, Wo_t);

  // 1) GEMM1 + fused qk-norm -> Qh/Kh/Vh bf16 head-major
  qkv_gemm_norm_kernel<<<dim3(QKV_COLS / 128, M / 128), 256, 0, stream>>>(
      Xb, Wqkv_t, tau, Qh, Kh, Vh);

  // 2) V -> V^T [BH][DH][S]
  vtrans_kernel<<<dim3(BATCH * NHEAD, SEQ / 64), 256, 0, stream>>>(Vh, Vt);

  // 3) causal MFMA flash attention -> attnb bf16 [B,S,D]
  //    grid 512: every block = exactly 33 steps, 2 blocks/CU, flat occupancy
  attn_kernel<<<dim3(512), 256, 0, stream>>>(Qh, Kh, Vt, attnb);

  // 4) out = attn @ Wo  (M=4096, N=1024, K=1024), f32 out
  sgemm_bf16_kernel<<<dim3(DMODEL / 128, M / 128), 256, 0, stream>>>(
      attnb, Wo_t, out, M, DMODEL, DMODEL);
}